// Round 2
// baseline (968.971 us; speedup 1.0000x reference)
//
#include <hip/hip_runtime.h>
#include <stdint.h>

#define T_TOK 4096
#define NE 8
#define HH 1024
#define II 2816
#define RRK 8
#define NPAIR (T_TOK*2)
#define ROWCAP 9216
#define MT_MAX 72
#define SCAL 2.0f

typedef short v8s __attribute__((ext_vector_type(8)));
typedef float v4f __attribute__((ext_vector_type(4)));

__device__ __forceinline__ unsigned short f2bf(float f){
  union { float f; unsigned u; } c; c.f = f;
  unsigned u = c.u;
  u += 0x7FFFu + ((u >> 16) & 1u);
  return (unsigned short)(u >> 16);
}
__device__ __forceinline__ float bf2f(unsigned short h){
  union { unsigned u; float f; } c; c.u = ((unsigned)h) << 16;
  return c.f;
}
__device__ __forceinline__ void gload16(const void* g, void* l){
  __builtin_amdgcn_global_load_lds(
      (const __attribute__((address_space(1))) unsigned int*)g,
      (__attribute__((address_space(3))) unsigned int*)l, 16, 0, 0);
}

// ---------------- routing ----------------
__global__ void route_count(const int* __restrict__ sel, int* __restrict__ counts,
                            int* __restrict__ bases, int* __restrict__ tile_e,
                            int* __restrict__ tile_r0){
  __shared__ int c[NE];
  int tid = threadIdx.x;
  if (tid < NE) c[tid] = 0;
  __syncthreads();
  for (int p = tid; p < NPAIR; p += 256) atomicAdd(&c[sel[p]], 1);
  __syncthreads();
  if (tid == 0){
    int b = 0;
    for (int e = 0; e < NE; e++){ counts[e] = c[e]; bases[e] = b; b += ((c[e] + 127) >> 7) << 7; }
    bases[NE] = b;
    int t = 0;
    for (int e = 0; e < NE; e++){
      int nt = (c[e] + 127) >> 7;
      for (int i = 0; i < nt; i++){ tile_e[t] = e; tile_r0[t] = bases[e] + i * 128; t++; }
    }
    for (; t < MT_MAX; t++){ tile_e[t] = -1; tile_r0[t] = 0; }
  }
}

__global__ void route_fill(const int* __restrict__ sel, const float* __restrict__ rw,
                           const int* __restrict__ bases,
                           int* __restrict__ row_token, int* __restrict__ row_expert,
                           float* __restrict__ row_w){
  int e = blockIdx.x;
  int lane = threadIdx.x;
  if (e == NE){
    for (int idx = bases[NE] + lane; idx < ROWCAP; idx += 64){
      row_token[idx] = -1; row_expert[idx] = 0; row_w[idx] = 0.f;
    }
    return;
  }
  int base = bases[e];
  int cnt = 0;
  for (int chunk = 0; chunk < NPAIR; chunk += 64){
    int p = chunk + lane;
    bool m = (sel[p] == e);
    unsigned long long mask = __ballot(m);
    if (m){
      int pos = __popcll(mask & ((1ull << lane) - 1ull));
      int dst = base + cnt + pos;
      row_token[dst] = p >> 1;
      row_expert[dst] = e;
      row_w[dst] = rw[p];
    }
    cnt += __popcll(mask);
  }
  int nb = bases[e + 1];
  for (int idx = base + cnt + lane; idx < nb; idx += 64){
    row_token[idx] = -1; row_expert[idx] = e; row_w[idx] = 0.f;
  }
}

// ---------------- weight transpose fp32[K][N] -> bf16[N][K] ----------------
__global__ void transpose_cvt(const float* __restrict__ W, unsigned short* __restrict__ Wt,
                              int K, int N){
  int e = blockIdx.y;
  int tilesK = K >> 6;
  int kt = (blockIdx.x % tilesK) * 64;
  int nt = (blockIdx.x / tilesK) * 64;
  __shared__ float tile[64][65];
  int tid = threadIdx.x;
  int r = tid >> 2;
  int c0 = (tid & 3) * 16;
  const float* src = W + (size_t)e * K * N + (size_t)(kt + r) * N + nt + c0;
  #pragma unroll
  for (int i = 0; i < 4; i++){
    float4 v = *(const float4*)(src + i * 4);
    tile[r][c0 + i*4 + 0] = v.x; tile[r][c0 + i*4 + 1] = v.y;
    tile[r][c0 + i*4 + 2] = v.z; tile[r][c0 + i*4 + 3] = v.w;
  }
  __syncthreads();
  union { unsigned short us[16]; uint4 q[2]; } pk;
  #pragma unroll
  for (int j = 0; j < 16; j++) pk.us[j] = f2bf(tile[c0 + j][r]);
  unsigned short* dst = Wt + (size_t)e * N * K + (size_t)(nt + r) * K + kt + c0;
  *(uint4*)(dst) = pk.q[0];
  *(uint4*)(dst + 8) = pk.q[1];
}

// ---------------- gather X rows -> bf16 ----------------
__global__ void gather_x(const float* __restrict__ x, const int* __restrict__ row_token,
                         unsigned short* __restrict__ Xg){
  int p = blockIdx.x; int tid = threadIdx.x;
  int tok = row_token[p];
  float4 v = make_float4(0.f, 0.f, 0.f, 0.f);
  if (tok >= 0) v = *(const float4*)(x + (size_t)tok * HH + tid * 4);
  uint2 o;
  o.x = (unsigned)f2bf(v.x) | ((unsigned)f2bf(v.y) << 16);
  o.y = (unsigned)f2bf(v.z) | ((unsigned)f2bf(v.w) << 16);
  *(uint2*)(Xg + (size_t)p * HH + tid * 4) = o;
}

// ---------------- LoRA xA = x @ A (fp32) ----------------
__global__ void xa_kernel(const float* __restrict__ x, const float* __restrict__ gA,
                          const float* __restrict__ uA, const int* __restrict__ row_token,
                          const int* __restrict__ row_expert,
                          float* __restrict__ xAg, float* __restrict__ xAu){
  int p = blockIdx.x; int tid = threadIdx.x;
  int tok = row_token[p]; int e = row_expert[p];
  float ag[8], au[8];
  #pragma unroll
  for (int r = 0; r < 8; r++){ ag[r] = 0.f; au[r] = 0.f; }
  if (tok >= 0){
    int k0 = tid * 4;
    float4 xv = *(const float4*)(x + (size_t)tok * HH + k0);
    const float* pg = gA + ((size_t)e * HH + k0) * RRK;
    const float* pu = uA + ((size_t)e * HH + k0) * RRK;
    float xs[4] = {xv.x, xv.y, xv.z, xv.w};
    #pragma unroll
    for (int j = 0; j < 4; j++){
      #pragma unroll
      for (int r = 0; r < 8; r++){
        ag[r] += xs[j] * pg[j * RRK + r];
        au[r] += xs[j] * pu[j * RRK + r];
      }
    }
  }
  __shared__ float redg[8][4], redu[8][4];
  int lane = tid & 63, wv = tid >> 6;
  #pragma unroll
  for (int r = 0; r < 8; r++){
    float v1 = ag[r], v2 = au[r];
    for (int off = 32; off > 0; off >>= 1){ v1 += __shfl_down(v1, off); v2 += __shfl_down(v2, off); }
    if (lane == 0){ redg[r][wv] = v1; redu[r][wv] = v2; }
  }
  __syncthreads();
  if (tid < 8) xAg[(size_t)p * RRK + tid] = redg[tid][0] + redg[tid][1] + redg[tid][2] + redg[tid][3];
  else if (tid < 16){ int r = tid - 8; xAu[(size_t)p * RRK + r] = redu[r][0] + redu[r][1] + redu[r][2] + redu[r][3]; }
}

// ---------------- LoRA hA = h @ down_A ----------------
__global__ void ha_kernel(const unsigned short* __restrict__ hbuf, const float* __restrict__ dA,
                          const int* __restrict__ row_expert, float* __restrict__ hAd){
  int p = blockIdx.x; int tid = threadIdx.x;
  int e = row_expert[p];
  float a[8];
  #pragma unroll
  for (int r = 0; r < 8; r++) a[r] = 0.f;
  for (int i = 0; i < 11; i++){
    int k = i * 256 + tid;
    float hv = bf2f(hbuf[(size_t)p * II + k]);
    const float* pd = dA + ((size_t)e * II + k) * RRK;
    #pragma unroll
    for (int r = 0; r < 8; r++) a[r] += hv * pd[r];
  }
  __shared__ float red[8][4];
  int lane = tid & 63, wv = tid >> 6;
  #pragma unroll
  for (int r = 0; r < 8; r++){
    float v = a[r];
    for (int off = 32; off > 0; off >>= 1) v += __shfl_down(v, off);
    if (lane == 0) red[r][wv] = v;
  }
  __syncthreads();
  if (tid < 8) hAd[(size_t)p * RRK + tid] = red[tid][0] + red[tid][1] + red[tid][2] + red[tid][3];
}

// ---------------- GEMM1: h = silu(x@Wg + lora) * (x@Wu + lora) ----------------
// 128x128 tile, BK=32, double-buffered 2-phase pipeline, 48KB LDS -> 3 blocks/CU
__launch_bounds__(256, 3)
__global__ void gemm1_kernel(const unsigned short* __restrict__ Xg,
                             const unsigned short* __restrict__ Wtg,
                             const unsigned short* __restrict__ Wtu,
                             const float* __restrict__ gateB,
                             const float* __restrict__ upB,
                             const float* __restrict__ xAg,
                             const float* __restrict__ xAu,
                             const int* __restrict__ tile_e,
                             const int* __restrict__ tile_r0,
                             unsigned short* __restrict__ hbuf){
  // XCD-chunked swizzle: 1584 blocks = 8 * 198, mt-fastest logical order
  int hw = blockIdx.x;
  int lg = (hw & 7) * 198 + (hw >> 3);
  int mt = lg % MT_MAX;
  int n0 = (lg / MT_MAX) * 128;

  int e = tile_e[mt];
  if (e < 0) return;
  int row0 = tile_r0[mt];

  __shared__ unsigned short lds[2][3 * 4096];  // 2 bufs x (A,Bg,Bu) x 128x32
  int tid = threadIdx.x;
  int lane = tid & 63;
  int w = tid >> 6;
  int wm = w >> 1, wn = w & 1;
  int g = lane >> 4, r16 = lane & 15;

  const unsigned short* srcA = Xg + (size_t)row0 * HH;
  const unsigned short* srcG = Wtg + ((size_t)e * II + n0) * HH;
  const unsigned short* srcU = Wtu + ((size_t)e * II + n0) * HH;

  v4f accg[4][4], accu[4][4];
  #pragma unroll
  for (int i = 0; i < 4; i++)
    #pragma unroll
    for (int j = 0; j < 4; j++){
      accg[i][j] = (v4f){0.f, 0.f, 0.f, 0.f};
      accu[i][j] = (v4f){0.f, 0.f, 0.f, 0.f};
    }

  int u0 = tid, u1 = tid + 256;
  int row_s0 = u0 >> 2, row_s1 = u1 >> 2;
  size_t goff0 = (size_t)row_s0 * HH + ((u0 & 3) ^ ((row_s0 >> 1) & 3)) * 8;
  size_t goff1 = (size_t)row_s1 * HH + ((u1 & 3) ^ ((row_s1 >> 1) & 3)) * 8;
  int ldst0 = (u0 & ~63) * 8, ldst1 = (u1 & ~63) * 8;

  const int NT = HH / 32;  // 32

  // prologue
  {
    unsigned short* buf = lds[0];
    gload16(srcA + goff0, buf + ldst0);
    gload16(srcG + goff0, buf + 4096 + ldst0);
    gload16(srcU + goff0, buf + 8192 + ldst0);
    gload16(srcA + goff1, buf + ldst1);
    gload16(srcG + goff1, buf + 4096 + ldst1);
    gload16(srcU + goff1, buf + 8192 + ldst1);
  }
  __syncthreads();

  for (int t = 0; t < NT; t++){
    if (t + 1 < NT){
      unsigned short* nbuf = lds[(t + 1) & 1];
      int ks = (t + 1) * 32;
      gload16(srcA + goff0 + ks, nbuf + ldst0);
      gload16(srcG + goff0 + ks, nbuf + 4096 + ldst0);
      gload16(srcU + goff0 + ks, nbuf + 8192 + ldst0);
      gload16(srcA + goff1 + ks, nbuf + ldst1);
      gload16(srcG + goff1 + ks, nbuf + 4096 + ldst1);
      gload16(srcU + goff1 + ks, nbuf + 8192 + ldst1);
    }
    const unsigned short* buf = lds[t & 1];
    v8s a[4], bg[4], bu[4];
    #pragma unroll
    for (int f = 0; f < 4; f++){
      int rowA = wm * 64 + f * 16 + r16;
      int ca = g ^ ((rowA >> 1) & 3);
      a[f] = *(const v8s*)(buf + rowA * 32 + ca * 8);
      int rowB = wn * 64 + f * 16 + r16;
      int cb = g ^ ((rowB >> 1) & 3);
      bg[f] = *(const v8s*)(buf + 4096 + rowB * 32 + cb * 8);
      bu[f] = *(const v8s*)(buf + 8192 + rowB * 32 + cb * 8);
    }
    #pragma unroll
    for (int fm = 0; fm < 4; fm++)
      #pragma unroll
      for (int fn = 0; fn < 4; fn++){
        accg[fm][fn] = __builtin_amdgcn_mfma_f32_16x16x32_bf16(a[fm], bg[fn], accg[fm][fn], 0, 0, 0);
        accu[fm][fn] = __builtin_amdgcn_mfma_f32_16x16x32_bf16(a[fm], bu[fn], accu[fm][fn], 0, 0, 0);
      }
    __syncthreads();
  }

  // epilogue: LoRA + silu, store h (reuse LDS)
  float* sxg = (float*)lds;          // [128][8]
  float* sxu = sxg + 1024;           // [128][8]
  float* sbg = sxu + 1024;           // [8][128]
  float* sbu = sbg + 1024;           // [8][128]
  if (tid < 128){
    #pragma unroll
    for (int r = 0; r < 8; r++){
      sxg[tid * 8 + r] = xAg[(size_t)(row0 + tid) * RRK + r];
      sxu[tid * 8 + r] = xAu[(size_t)(row0 + tid) * RRK + r];
    }
  } else {
    int tt = tid - 128;
    #pragma unroll
    for (int r = 0; r < 8; r++){
      sbg[r * 128 + tt] = gateB[((size_t)e * RRK + r) * II + n0 + tt];
      sbu[r * 128 + tt] = upB[((size_t)e * RRK + r) * II + n0 + tt];
    }
  }
  __syncthreads();
  #pragma unroll
  for (int fm = 0; fm < 4; fm++)
    #pragma unroll
    for (int fn = 0; fn < 4; fn++)
      #pragma unroll
      for (int r = 0; r < 4; r++){
        int lrow = wm * 64 + fm * 16 + g * 4 + r;
        int lcol = wn * 64 + fn * 16 + r16;
        float gg = accg[fm][fn][r];
        float uu = accu[fm][fn][r];
        float dg = 0.f, du = 0.f;
        #pragma unroll
        for (int j = 0; j < 8; j++){
          dg += sxg[lrow * 8 + j] * sbg[j * 128 + lcol];
          du += sxu[lrow * 8 + j] * sbu[j * 128 + lcol];
        }
        gg += SCAL * dg; uu += SCAL * du;
        float hh = (gg / (1.f + __expf(-gg))) * uu;
        hbuf[(size_t)(row0 + lrow) * II + n0 + lcol] = f2bf(hh);
      }
}

// ---------------- GEMM2: out += w * (h@Wd + lora) ----------------
// 128x128 tile, BK=64, double-buffered 2-phase pipeline, 64KB LDS -> 2 blocks/CU
__launch_bounds__(256, 2)
__global__ void gemm2_kernel(const unsigned short* __restrict__ hbuf,
                             const unsigned short* __restrict__ Wtd,
                             const float* __restrict__ downB,
                             const float* __restrict__ hAd,
                             const int* __restrict__ tile_e,
                             const int* __restrict__ tile_r0,
                             const int* __restrict__ row_token,
                             const float* __restrict__ row_w,
                             float* __restrict__ out){
  // XCD-chunked swizzle: 576 blocks = 8 * 72, mt-fastest logical order
  int hw = blockIdx.x;
  int lg = (hw & 7) * 72 + (hw >> 3);
  int mt = lg % MT_MAX;
  int n0 = (lg / MT_MAX) * 128;

  int e = tile_e[mt];
  if (e < 0) return;
  int row0 = tile_r0[mt];

  __shared__ unsigned short lds[2][2 * 8192];  // 2 bufs x (A,B) x 128x64
  int tid = threadIdx.x;
  int lane = tid & 63;
  int w = tid >> 6;
  int wm = w >> 1, wn = w & 1;
  int g = lane >> 4, r16 = lane & 15;

  const unsigned short* srcA = hbuf + (size_t)row0 * II;
  const unsigned short* srcB = Wtd + ((size_t)e * HH + n0) * II;

  v4f acc[4][4];
  #pragma unroll
  for (int i = 0; i < 4; i++)
    #pragma unroll
    for (int j = 0; j < 4; j++) acc[i][j] = (v4f){0.f, 0.f, 0.f, 0.f};

  int us[4], rows[4], ldst[4];
  size_t goffs[4];
  #pragma unroll
  for (int i = 0; i < 4; i++){
    us[i] = tid + i * 256;
    rows[i] = us[i] >> 3;
    goffs[i] = (size_t)rows[i] * II + ((us[i] & 7) ^ (rows[i] & 7)) * 8;
    ldst[i] = (us[i] & ~63) * 8;
  }

  const int NT = II / 64;  // 44

  {
    unsigned short* buf = lds[0];
    #pragma unroll
    for (int i = 0; i < 4; i++){
      gload16(srcA + goffs[i], buf + ldst[i]);
      gload16(srcB + goffs[i], buf + 8192 + ldst[i]);
    }
  }
  __syncthreads();

  for (int t = 0; t < NT; t++){
    if (t + 1 < NT){
      unsigned short* nbuf = lds[(t + 1) & 1];
      int ks = (t + 1) * 64;
      #pragma unroll
      for (int i = 0; i < 4; i++){
        gload16(srcA + goffs[i] + ks, nbuf + ldst[i]);
        gload16(srcB + goffs[i] + ks, nbuf + 8192 + ldst[i]);
      }
    }
    const unsigned short* buf = lds[t & 1];
    #pragma unroll
    for (int kk = 0; kk < 2; kk++){
      v8s a[4], b[4];
      #pragma unroll
      for (int f = 0; f < 4; f++){
        int rowA = wm * 64 + f * 16 + r16;
        int ca = ((kk << 2) | g) ^ (rowA & 7);
        a[f] = *(const v8s*)(buf + rowA * 64 + ca * 8);
        int rowB = wn * 64 + f * 16 + r16;
        int cb = ((kk << 2) | g) ^ (rowB & 7);
        b[f] = *(const v8s*)(buf + 8192 + rowB * 64 + cb * 8);
      }
      #pragma unroll
      for (int fm = 0; fm < 4; fm++)
        #pragma unroll
        for (int fn = 0; fn < 4; fn++)
          acc[fm][fn] = __builtin_amdgcn_mfma_f32_16x16x32_bf16(a[fm], b[fn], acc[fm][fn], 0, 0, 0);
    }
    __syncthreads();
  }

  float* shA = (float*)lds;         // [128][8]
  float* sdb = shA + 1024;          // [8][128]
  if (tid < 128){
    #pragma unroll
    for (int r = 0; r < 8; r++) shA[tid * 8 + r] = hAd[(size_t)(row0 + tid) * RRK + r];
  } else {
    int tt = tid - 128;
    #pragma unroll
    for (int r = 0; r < 8; r++) sdb[r * 128 + tt] = downB[((size_t)e * RRK + r) * HH + n0 + tt];
  }
  __syncthreads();
  #pragma unroll
  for (int fm = 0; fm < 4; fm++)
    #pragma unroll
    for (int fn = 0; fn < 4; fn++)
      #pragma unroll
      for (int r = 0; r < 4; r++){
        int lrow = wm * 64 + fm * 16 + g * 4 + r;
        int lcol = wn * 64 + fn * 16 + r16;
        float y = acc[fm][fn][r];
        float dd = 0.f;
        #pragma unroll
        for (int j = 0; j < 8; j++) dd += shA[lrow * 8 + j] * sdb[j * 128 + lcol];
        y += SCAL * dd;
        int grow = row0 + lrow;
        int tok = row_token[grow];
        if (tok >= 0) atomicAdd(&out[(size_t)tok * HH + n0 + lcol], row_w[grow] * y);
      }
}

extern "C" void kernel_launch(void* const* d_in, const int* in_sizes, int n_in,
                              void* d_out, int out_size, void* d_ws, size_t ws_size,
                              hipStream_t stream){
  const float* x         = (const float*)d_in[0];
  const float* rw        = (const float*)d_in[1];
  const int*   sel       = (const int*)d_in[2];
  const float* gate_proj = (const float*)d_in[3];
  const float* up_proj   = (const float*)d_in[4];
  const float* down_proj = (const float*)d_in[5];
  const float* gate_A    = (const float*)d_in[6];
  const float* gate_B    = (const float*)d_in[7];
  const float* up_A      = (const float*)d_in[8];
  const float* up_B      = (const float*)d_in[9];
  const float* down_A    = (const float*)d_in[10];
  const float* down_B    = (const float*)d_in[11];
  float* out = (float*)d_out;
  char* ws = (char*)d_ws;

  constexpr size_t OFF_COUNTS = 0;
  constexpr size_t OFF_BASES  = 256;
  constexpr size_t OFF_TILE_E = 512;
  constexpr size_t OFF_TILE_R0 = 1024;
  constexpr size_t OFF_ROWTOK = 2048;
  constexpr size_t OFF_ROWEXP = OFF_ROWTOK + (size_t)ROWCAP * 4;
  constexpr size_t OFF_ROWW   = OFF_ROWEXP + (size_t)ROWCAP * 4;
  constexpr size_t OFF_XAG    = OFF_ROWW + (size_t)ROWCAP * 4;
  constexpr size_t OFF_XAU    = OFF_XAG + (size_t)ROWCAP * RRK * 4;
  constexpr size_t OFF_HAD    = OFF_XAU + (size_t)ROWCAP * RRK * 4;
  constexpr size_t OFF_XG     = OFF_HAD + (size_t)ROWCAP * RRK * 4;
  constexpr size_t OFF_H      = OFF_XG + (size_t)ROWCAP * HH * 2;
  constexpr size_t OFF_WTG    = OFF_H + (size_t)ROWCAP * II * 2;
  constexpr size_t OFF_WTU    = OFF_WTG + (size_t)NE * HH * II * 2;
  constexpr size_t OFF_WTD    = OFF_WTU + (size_t)NE * HH * II * 2;

  int* counts   = (int*)(ws + OFF_COUNTS);
  int* bases    = (int*)(ws + OFF_BASES);
  int* tile_e   = (int*)(ws + OFF_TILE_E);
  int* tile_r0  = (int*)(ws + OFF_TILE_R0);
  int* row_token = (int*)(ws + OFF_ROWTOK);
  int* row_expert = (int*)(ws + OFF_ROWEXP);
  float* row_w  = (float*)(ws + OFF_ROWW);
  float* xAg    = (float*)(ws + OFF_XAG);
  float* xAu    = (float*)(ws + OFF_XAU);
  float* hAd    = (float*)(ws + OFF_HAD);
  unsigned short* Xg   = (unsigned short*)(ws + OFF_XG);
  unsigned short* hbuf = (unsigned short*)(ws + OFF_H);
  unsigned short* Wtg  = (unsigned short*)(ws + OFF_WTG);
  unsigned short* Wtu  = (unsigned short*)(ws + OFF_WTU);
  unsigned short* Wtd  = (unsigned short*)(ws + OFF_WTD);

  hipMemsetAsync(d_out, 0, (size_t)T_TOK * HH * sizeof(float), stream);
  route_count<<<1, 256, 0, stream>>>(sel, counts, bases, tile_e, tile_r0);
  route_fill<<<NE + 1, 64, 0, stream>>>(sel, rw, bases, row_token, row_expert, row_w);
  transpose_cvt<<<dim3((HH >> 6) * (II >> 6), NE), 256, 0, stream>>>(gate_proj, Wtg, HH, II);
  transpose_cvt<<<dim3((HH >> 6) * (II >> 6), NE), 256, 0, stream>>>(up_proj, Wtu, HH, II);
  transpose_cvt<<<dim3((II >> 6) * (HH >> 6), NE), 256, 0, stream>>>(down_proj, Wtd, II, HH);
  gather_x<<<ROWCAP, 256, 0, stream>>>(x, row_token, Xg);
  xa_kernel<<<ROWCAP, 256, 0, stream>>>(x, gate_A, up_A, row_token, row_expert, xAg, xAu);
  gemm1_kernel<<<MT_MAX * (II / 128), 256, 0, stream>>>(Xg, Wtg, Wtu, gate_B, up_B, xAg, xAu,
                                                        tile_e, tile_r0, hbuf);
  ha_kernel<<<ROWCAP, 256, 0, stream>>>(hbuf, down_A, row_expert, hAd);
  gemm2_kernel<<<MT_MAX * (HH / 128), 256, 0, stream>>>(hbuf, Wtd, down_B, hAd, tile_e, tile_r0,
                                                        row_token, row_w, out);
}

// Round 3
// 725.690 us; speedup vs baseline: 1.3352x; 1.3352x over previous
//
#include <hip/hip_runtime.h>
#include <stdint.h>

#define T_TOK 4096
#define NE 8
#define HH 1024
#define II 2816
#define HE 1056   // HH + 32 ext (lora-g 8, lora-u 8, zero 16)
#define IE 2848   // II + 32 ext (lora-d 8, zero 24)
#define RRK 8
#define NPAIR (T_TOK*2)
#define ROWCAP 9216
#define MT_MAX 72
#define SCAL 2.0f

typedef short v8s __attribute__((ext_vector_type(8)));
typedef float v4f __attribute__((ext_vector_type(4)));

__device__ __forceinline__ unsigned short f2bf(float f){
  union { float f; unsigned u; } c; c.f = f;
  unsigned u = c.u;
  u += 0x7FFFu + ((u >> 16) & 1u);
  return (unsigned short)(u >> 16);
}
__device__ __forceinline__ float bf2f(unsigned short h){
  union { unsigned u; float f; } c; c.u = ((unsigned)h) << 16;
  return c.f;
}
__device__ __forceinline__ void gload16(const void* g, void* l){
  __builtin_amdgcn_global_load_lds(
      (const __attribute__((address_space(1))) unsigned int*)g,
      (__attribute__((address_space(3))) unsigned int*)l, 16, 0, 0);
}

// ---------------- routing ----------------
__global__ void route_count(const int* __restrict__ sel, int* __restrict__ counts,
                            int* __restrict__ bases, int* __restrict__ tile_e,
                            int* __restrict__ tile_r0){
  __shared__ int c[NE];
  int tid = threadIdx.x;
  if (tid < NE) c[tid] = 0;
  __syncthreads();
  for (int p = tid; p < NPAIR; p += 256) atomicAdd(&c[sel[p]], 1);
  __syncthreads();
  if (tid == 0){
    int b = 0;
    for (int e = 0; e < NE; e++){ counts[e] = c[e]; bases[e] = b; b += ((c[e] + 127) >> 7) << 7; }
    bases[NE] = b;
    int t = 0;
    for (int e = 0; e < NE; e++){
      int nt = (c[e] + 127) >> 7;
      for (int i = 0; i < nt; i++){ tile_e[t] = e; tile_r0[t] = bases[e] + i * 128; t++; }
    }
    for (; t < MT_MAX; t++){ tile_e[t] = -1; tile_r0[t] = 0; }
  }
}

__global__ void route_fill(const int* __restrict__ sel, const float* __restrict__ rw,
                           const int* __restrict__ bases,
                           int* __restrict__ row_token, int* __restrict__ row_expert,
                           float* __restrict__ row_w){
  int e = blockIdx.x;
  int lane = threadIdx.x;
  if (e == NE){
    for (int idx = bases[NE] + lane; idx < ROWCAP; idx += 64){
      row_token[idx] = -1; row_expert[idx] = 0; row_w[idx] = 0.f;
    }
    return;
  }
  int base = bases[e];
  int cnt = 0;
  for (int chunk = 0; chunk < NPAIR; chunk += 64){
    int p = chunk + lane;
    bool m = (sel[p] == e);
    unsigned long long mask = __ballot(m);
    if (m){
      int pos = __popcll(mask & ((1ull << lane) - 1ull));
      int dst = base + cnt + pos;
      row_token[dst] = p >> 1;
      row_expert[dst] = e;
      row_w[dst] = rw[p];
    }
    cnt += __popcll(mask);
  }
  int nb = bases[e + 1];
  for (int idx = base + cnt + lane; idx < nb; idx += 64){
    row_token[idx] = -1; row_expert[idx] = e; row_w[idx] = 0.f;
  }
}

// ---------------- weight transpose fp32[K][N] -> bf16[N][KE] ----------------
__global__ void transpose_cvt(const float* __restrict__ W, unsigned short* __restrict__ Wt,
                              int K, int N, int KE){
  int e = blockIdx.y;
  int tilesK = K >> 6;
  int kt = (blockIdx.x % tilesK) * 64;
  int nt = (blockIdx.x / tilesK) * 64;
  __shared__ float tile[64][65];
  int tid = threadIdx.x;
  int r = tid >> 2;
  int c0 = (tid & 3) * 16;
  const float* src = W + (size_t)e * K * N + (size_t)(kt + r) * N + nt + c0;
  #pragma unroll
  for (int i = 0; i < 4; i++){
    float4 v = *(const float4*)(src + i * 4);
    tile[r][c0 + i*4 + 0] = v.x; tile[r][c0 + i*4 + 1] = v.y;
    tile[r][c0 + i*4 + 2] = v.z; tile[r][c0 + i*4 + 3] = v.w;
  }
  __syncthreads();
  union { unsigned short us[16]; uint4 q[2]; } pk;
  #pragma unroll
  for (int j = 0; j < 16; j++) pk.us[j] = f2bf(tile[c0 + j][r]);
  unsigned short* dst = Wt + (size_t)e * N * KE + (size_t)(nt + r) * KE + kt + c0;
  *(uint4*)(dst) = pk.q[0];
  *(uint4*)(dst + 8) = pk.q[1];
}

// ---------------- lora-B ext columns for gate/up: Wt[n][1024+j] ----------------
__global__ void ext_fill_pair(unsigned short* __restrict__ Wtg, unsigned short* __restrict__ Wtu,
                              const float* __restrict__ gB, const float* __restrict__ uB){
  int idx = blockIdx.x * 256 + threadIdx.x;
  if (idx >= NE * II) return;
  int e = idx / II, n = idx % II;
  unsigned short* g = Wtg + ((size_t)e * II + n) * HE + HH;
  unsigned short* u = Wtu + ((size_t)e * II + n) * HE + HH;
  #pragma unroll
  for (int j = 0; j < 8; j++){
    g[j] = f2bf(gB[((size_t)e * RRK + j) * II + n]);
    u[j] = 0;
    g[8 + j] = 0;
    u[8 + j] = f2bf(uB[((size_t)e * RRK + j) * II + n]);
  }
  #pragma unroll
  for (int j = 16; j < 32; j++){ g[j] = 0; u[j] = 0; }
}

__global__ void ext_fill_down(unsigned short* __restrict__ Wtd, const float* __restrict__ dB){
  int idx = blockIdx.x * 256 + threadIdx.x;
  if (idx >= NE * HH) return;
  int e = idx / HH, n = idx % HH;
  unsigned short* d = Wtd + ((size_t)e * HH + n) * IE + II;
  #pragma unroll
  for (int j = 0; j < 8; j++) d[j] = f2bf(dB[((size_t)e * RRK + j) * HH + n]);
  #pragma unroll
  for (int j = 8; j < 32; j++) d[j] = 0;
}

// ---------------- gather X rows -> bf16 (cols 0..1023) ----------------
__global__ void gather_x(const float* __restrict__ x, const int* __restrict__ row_token,
                         unsigned short* __restrict__ Xg){
  int p = blockIdx.x; int tid = threadIdx.x;
  int tok = row_token[p];
  float4 v = make_float4(0.f, 0.f, 0.f, 0.f);
  if (tok >= 0) v = *(const float4*)(x + (size_t)tok * HH + tid * 4);
  uint2 o;
  o.x = (unsigned)f2bf(v.x) | ((unsigned)f2bf(v.y) << 16);
  o.y = (unsigned)f2bf(v.z) | ((unsigned)f2bf(v.w) << 16);
  *(uint2*)(Xg + (size_t)p * HE + tid * 4) = o;
}

// ---------------- LoRA xA: write SCAL*(x@A) into Xg ext cols ----------------
__global__ void xa_kernel(const float* __restrict__ x, const float* __restrict__ gA,
                          const float* __restrict__ uA, const int* __restrict__ row_token,
                          const int* __restrict__ row_expert,
                          unsigned short* __restrict__ Xg){
  int p = blockIdx.x; int tid = threadIdx.x;
  int tok = row_token[p]; int e = row_expert[p];
  float ag[8], au[8];
  #pragma unroll
  for (int r = 0; r < 8; r++){ ag[r] = 0.f; au[r] = 0.f; }
  if (tok >= 0){
    int k0 = tid * 4;
    float4 xv = *(const float4*)(x + (size_t)tok * HH + k0);
    const float* pg = gA + ((size_t)e * HH + k0) * RRK;
    const float* pu = uA + ((size_t)e * HH + k0) * RRK;
    float xs[4] = {xv.x, xv.y, xv.z, xv.w};
    #pragma unroll
    for (int j = 0; j < 4; j++){
      #pragma unroll
      for (int r = 0; r < 8; r++){
        ag[r] += xs[j] * pg[j * RRK + r];
        au[r] += xs[j] * pu[j * RRK + r];
      }
    }
  }
  __shared__ float redg[8][4], redu[8][4];
  int lane = tid & 63, wv = tid >> 6;
  #pragma unroll
  for (int r = 0; r < 8; r++){
    float v1 = ag[r], v2 = au[r];
    for (int off = 32; off > 0; off >>= 1){ v1 += __shfl_down(v1, off); v2 += __shfl_down(v2, off); }
    if (lane == 0){ redg[r][wv] = v1; redu[r][wv] = v2; }
  }
  __syncthreads();
  if (tid < 8)
    Xg[(size_t)p * HE + HH + tid] = f2bf(SCAL * (redg[tid][0] + redg[tid][1] + redg[tid][2] + redg[tid][3]));
  else if (tid < 16){
    int r = tid - 8;
    Xg[(size_t)p * HE + HH + 8 + r] = f2bf(SCAL * (redu[r][0] + redu[r][1] + redu[r][2] + redu[r][3]));
  } else if (tid < 32){
    Xg[(size_t)p * HE + HH + tid] = 0;
  }
}

// ---------------- LoRA hA: write SCAL*(h@down_A) into hbuf ext cols ----------------
__global__ void ha_kernel(const unsigned short* __restrict__ hbuf, const float* __restrict__ dA,
                          const int* __restrict__ row_expert, unsigned short* __restrict__ hout){
  int p = blockIdx.x; int tid = threadIdx.x;
  int e = row_expert[p];
  float a[8];
  #pragma unroll
  for (int r = 0; r < 8; r++) a[r] = 0.f;
  for (int i = 0; i < 11; i++){
    int k = i * 256 + tid;
    float hv = bf2f(hbuf[(size_t)p * IE + k]);
    const float* pd = dA + ((size_t)e * II + k) * RRK;
    #pragma unroll
    for (int r = 0; r < 8; r++) a[r] += hv * pd[r];
  }
  __shared__ float red[8][4];
  int lane = tid & 63, wv = tid >> 6;
  #pragma unroll
  for (int r = 0; r < 8; r++){
    float v = a[r];
    for (int off = 32; off > 0; off >>= 1) v += __shfl_down(v, off);
    if (lane == 0) red[r][wv] = v;
  }
  __syncthreads();
  if (tid < 8)
    hout[(size_t)p * IE + II + tid] = f2bf(SCAL * (red[tid][0] + red[tid][1] + red[tid][2] + red[tid][3]));
  else if (tid < 32)
    hout[(size_t)p * IE + II + tid] = 0;
}

// ---------------- GEMM1: h = silu(x'@Wg') * (x'@Wu'), lora folded into K-ext ----------------
// 128x128 tile, BK=32, dbuf, 48KB LDS, 3 blocks/CU
__launch_bounds__(256, 3)
__global__ void gemm1_kernel(const unsigned short* __restrict__ Xg,
                             const unsigned short* __restrict__ Wtg,
                             const unsigned short* __restrict__ Wtu,
                             const int* __restrict__ tile_e,
                             const int* __restrict__ tile_r0,
                             unsigned short* __restrict__ hbuf){
  // XCD-chunked, n0-fastest: XCD k owns mt [9k,9k+9) x all 22 n0
  int hw = blockIdx.x;
  int lg = (hw & 7) * 198 + (hw >> 3);
  int mt = lg / 22;
  int n0 = (lg % 22) * 128;

  int e = tile_e[mt];
  if (e < 0) return;
  int row0 = tile_r0[mt];

  __shared__ unsigned short lds[2][3 * 4096];  // 2 bufs x (A,Bg,Bu) x 128x32
  int tid = threadIdx.x;
  int lane = tid & 63;
  int w = tid >> 6;
  int wm = w >> 1, wn = w & 1;
  int g = lane >> 4, r16 = lane & 15;

  const unsigned short* srcA = Xg + (size_t)row0 * HE;
  const unsigned short* srcG = Wtg + ((size_t)e * II + n0) * HE;
  const unsigned short* srcU = Wtu + ((size_t)e * II + n0) * HE;

  v4f accg[4][4], accu[4][4];
  #pragma unroll
  for (int i = 0; i < 4; i++)
    #pragma unroll
    for (int j = 0; j < 4; j++){
      accg[i][j] = (v4f){0.f, 0.f, 0.f, 0.f};
      accu[i][j] = (v4f){0.f, 0.f, 0.f, 0.f};
    }

  int u0 = tid, u1 = tid + 256;
  int row_s0 = u0 >> 2, row_s1 = u1 >> 2;
  size_t goff0 = (size_t)row_s0 * HE + ((u0 & 3) ^ ((row_s0 >> 1) & 3)) * 8;
  size_t goff1 = (size_t)row_s1 * HE + ((u1 & 3) ^ ((row_s1 >> 1) & 3)) * 8;
  int ldst0 = (u0 & ~63) * 8, ldst1 = (u1 & ~63) * 8;

  const int NT = HE / 32;  // 33

  {
    unsigned short* buf = lds[0];
    gload16(srcA + goff0, buf + ldst0);
    gload16(srcG + goff0, buf + 4096 + ldst0);
    gload16(srcU + goff0, buf + 8192 + ldst0);
    gload16(srcA + goff1, buf + ldst1);
    gload16(srcG + goff1, buf + 4096 + ldst1);
    gload16(srcU + goff1, buf + 8192 + ldst1);
  }
  __syncthreads();

  for (int t = 0; t < NT; t++){
    if (t + 1 < NT){
      unsigned short* nbuf = lds[(t + 1) & 1];
      int ks = (t + 1) * 32;
      gload16(srcA + goff0 + ks, nbuf + ldst0);
      gload16(srcG + goff0 + ks, nbuf + 4096 + ldst0);
      gload16(srcU + goff0 + ks, nbuf + 8192 + ldst0);
      gload16(srcA + goff1 + ks, nbuf + ldst1);
      gload16(srcG + goff1 + ks, nbuf + 4096 + ldst1);
      gload16(srcU + goff1 + ks, nbuf + 8192 + ldst1);
    }
    const unsigned short* buf = lds[t & 1];
    v8s a[4], bg[4], bu[4];
    #pragma unroll
    for (int f = 0; f < 4; f++){
      int rowA = wm * 64 + f * 16 + r16;
      int ca = g ^ ((rowA >> 1) & 3);
      a[f] = *(const v8s*)(buf + rowA * 32 + ca * 8);
      int rowB = wn * 64 + f * 16 + r16;
      int cb = g ^ ((rowB >> 1) & 3);
      bg[f] = *(const v8s*)(buf + 4096 + rowB * 32 + cb * 8);
      bu[f] = *(const v8s*)(buf + 8192 + rowB * 32 + cb * 8);
    }
    #pragma unroll
    for (int fm = 0; fm < 4; fm++)
      #pragma unroll
      for (int fn = 0; fn < 4; fn++){
        accg[fm][fn] = __builtin_amdgcn_mfma_f32_16x16x32_bf16(a[fm], bg[fn], accg[fm][fn], 0, 0, 0);
        accu[fm][fn] = __builtin_amdgcn_mfma_f32_16x16x32_bf16(a[fm], bu[fn], accu[fm][fn], 0, 0, 0);
      }
    __syncthreads();
  }

  // epilogue: silu*up -> LDS tile (chunk-XOR swizzle) -> streamed full-line writes
  unsigned short* sh = (unsigned short*)lds;  // [128][128] bf16, 32KB
  #pragma unroll
  for (int fm = 0; fm < 4; fm++)
    #pragma unroll
    for (int fn = 0; fn < 4; fn++)
      #pragma unroll
      for (int r = 0; r < 4; r++){
        int lrow = wm * 64 + fm * 16 + g * 4 + r;
        int lcol = wn * 64 + fn * 16 + r16;
        float gg = accg[fm][fn][r];
        float uu = accu[fm][fn][r];
        float hh = (gg / (1.f + __expf(-gg))) * uu;
        int ch = (lcol >> 3) ^ (lrow & 7);
        sh[lrow * 128 + ch * 8 + (lcol & 7)] = f2bf(hh);
      }
  __syncthreads();
  #pragma unroll
  for (int pass = 0; pass < 8; pass++){
    int idx = pass * 256 + tid;   // 16B chunk id
    int row = idx >> 4;
    int ch = idx & 15;
    int chs = ch ^ (row & 7);
    v8s val = *(const v8s*)(sh + row * 128 + chs * 8);
    *(v8s*)(hbuf + (size_t)(row0 + row) * IE + n0 + ch * 8) = val;
  }
}

// ---------------- GEMM2: out += w * (h'@Wd'), lora folded into K-ext ----------------
// 128x128 tile, BK=32, dbuf, 32KB LDS, 3 blocks/CU
__launch_bounds__(256, 3)
__global__ void gemm2_kernel(const unsigned short* __restrict__ hbuf,
                             const unsigned short* __restrict__ Wtd,
                             const int* __restrict__ tile_e,
                             const int* __restrict__ tile_r0,
                             const int* __restrict__ row_token,
                             const float* __restrict__ row_w,
                             float* __restrict__ out){
  // XCD-chunked, n0-fastest: XCD k owns mt [9k,9k+9) x all 8 n0
  int hw = blockIdx.x;
  int lg = (hw & 7) * 72 + (hw >> 3);
  int mt = lg / 8;
  int n0 = (lg % 8) * 128;

  int e = tile_e[mt];
  if (e < 0) return;
  int row0 = tile_r0[mt];

  __shared__ unsigned short lds[2][2 * 4096];  // 2 bufs x (A,B) x 128x32
  int tid = threadIdx.x;
  int lane = tid & 63;
  int w = tid >> 6;
  int wm = w >> 1, wn = w & 1;
  int g = lane >> 4, r16 = lane & 15;

  const unsigned short* srcA = hbuf + (size_t)row0 * IE;
  const unsigned short* srcB = Wtd + ((size_t)e * HH + n0) * IE;

  v4f acc[4][4];
  #pragma unroll
  for (int i = 0; i < 4; i++)
    #pragma unroll
    for (int j = 0; j < 4; j++) acc[i][j] = (v4f){0.f, 0.f, 0.f, 0.f};

  int u0 = tid, u1 = tid + 256;
  int row_s0 = u0 >> 2, row_s1 = u1 >> 2;
  size_t goff0 = (size_t)row_s0 * IE + ((u0 & 3) ^ ((row_s0 >> 1) & 3)) * 8;
  size_t goff1 = (size_t)row_s1 * IE + ((u1 & 3) ^ ((row_s1 >> 1) & 3)) * 8;
  int ldst0 = (u0 & ~63) * 8, ldst1 = (u1 & ~63) * 8;

  const int NT = IE / 32;  // 89

  {
    unsigned short* buf = lds[0];
    gload16(srcA + goff0, buf + ldst0);
    gload16(srcB + goff0, buf + 4096 + ldst0);
    gload16(srcA + goff1, buf + ldst1);
    gload16(srcB + goff1, buf + 4096 + ldst1);
  }
  __syncthreads();

  for (int t = 0; t < NT; t++){
    if (t + 1 < NT){
      unsigned short* nbuf = lds[(t + 1) & 1];
      int ks = (t + 1) * 32;
      gload16(srcA + goff0 + ks, nbuf + ldst0);
      gload16(srcB + goff0 + ks, nbuf + 4096 + ldst0);
      gload16(srcA + goff1 + ks, nbuf + ldst1);
      gload16(srcB + goff1 + ks, nbuf + 4096 + ldst1);
    }
    const unsigned short* buf = lds[t & 1];
    v8s a[4], b[4];
    #pragma unroll
    for (int f = 0; f < 4; f++){
      int rowA = wm * 64 + f * 16 + r16;
      int ca = g ^ ((rowA >> 1) & 3);
      a[f] = *(const v8s*)(buf + rowA * 32 + ca * 8);
      int rowB = wn * 64 + f * 16 + r16;
      int cb = g ^ ((rowB >> 1) & 3);
      b[f] = *(const v8s*)(buf + 4096 + rowB * 32 + cb * 8);
    }
    #pragma unroll
    for (int fm = 0; fm < 4; fm++)
      #pragma unroll
      for (int fn = 0; fn < 4; fn++)
        acc[fm][fn] = __builtin_amdgcn_mfma_f32_16x16x32_bf16(a[fm], b[fn], acc[fm][fn], 0, 0, 0);
    __syncthreads();
  }

  #pragma unroll
  for (int fm = 0; fm < 4; fm++)
    #pragma unroll
    for (int fn = 0; fn < 4; fn++)
      #pragma unroll
      for (int r = 0; r < 4; r++){
        int lrow = wm * 64 + fm * 16 + g * 4 + r;
        int lcol = wn * 64 + fn * 16 + r16;
        int grow = row0 + lrow;
        int tok = row_token[grow];
        if (tok >= 0)
          atomicAdd(&out[(size_t)tok * HH + n0 + lcol], row_w[grow] * acc[fm][fn][r]);
      }
}

extern "C" void kernel_launch(void* const* d_in, const int* in_sizes, int n_in,
                              void* d_out, int out_size, void* d_ws, size_t ws_size,
                              hipStream_t stream){
  const float* x         = (const float*)d_in[0];
  const float* rw        = (const float*)d_in[1];
  const int*   sel       = (const int*)d_in[2];
  const float* gate_proj = (const float*)d_in[3];
  const float* up_proj   = (const float*)d_in[4];
  const float* down_proj = (const float*)d_in[5];
  const float* gate_A    = (const float*)d_in[6];
  const float* gate_B    = (const float*)d_in[7];
  const float* up_A      = (const float*)d_in[8];
  const float* up_B      = (const float*)d_in[9];
  const float* down_A    = (const float*)d_in[10];
  const float* down_B    = (const float*)d_in[11];
  float* out = (float*)d_out;
  char* ws = (char*)d_ws;

  constexpr size_t OFF_COUNTS = 0;
  constexpr size_t OFF_BASES  = 256;
  constexpr size_t OFF_TILE_E = 512;
  constexpr size_t OFF_TILE_R0 = 1024;
  constexpr size_t OFF_ROWTOK = 2048;
  constexpr size_t OFF_ROWEXP = OFF_ROWTOK + (size_t)ROWCAP * 4;
  constexpr size_t OFF_ROWW   = OFF_ROWEXP + (size_t)ROWCAP * 4;
  constexpr size_t OFF_XG     = OFF_ROWW + (size_t)ROWCAP * 4;
  constexpr size_t OFF_H      = OFF_XG + (size_t)ROWCAP * HE * 2;
  constexpr size_t OFF_WTG    = OFF_H + (size_t)ROWCAP * IE * 2;
  constexpr size_t OFF_WTU    = OFF_WTG + (size_t)NE * II * HE * 2;
  constexpr size_t OFF_WTD    = OFF_WTU + (size_t)NE * II * HE * 2;

  int* counts   = (int*)(ws + OFF_COUNTS);
  int* bases    = (int*)(ws + OFF_BASES);
  int* tile_e   = (int*)(ws + OFF_TILE_E);
  int* tile_r0  = (int*)(ws + OFF_TILE_R0);
  int* row_token = (int*)(ws + OFF_ROWTOK);
  int* row_expert = (int*)(ws + OFF_ROWEXP);
  float* row_w  = (float*)(ws + OFF_ROWW);
  unsigned short* Xg   = (unsigned short*)(ws + OFF_XG);
  unsigned short* hbuf = (unsigned short*)(ws + OFF_H);
  unsigned short* Wtg  = (unsigned short*)(ws + OFF_WTG);
  unsigned short* Wtu  = (unsigned short*)(ws + OFF_WTU);
  unsigned short* Wtd  = (unsigned short*)(ws + OFF_WTD);

  hipMemsetAsync(d_out, 0, (size_t)T_TOK * HH * sizeof(float), stream);
  route_count<<<1, 256, 0, stream>>>(sel, counts, bases, tile_e, tile_r0);
  route_fill<<<NE + 1, 64, 0, stream>>>(sel, rw, bases, row_token, row_expert, row_w);
  transpose_cvt<<<dim3((HH >> 6) * (II >> 6), NE), 256, 0, stream>>>(gate_proj, Wtg, HH, II, HE);
  transpose_cvt<<<dim3((HH >> 6) * (II >> 6), NE), 256, 0, stream>>>(up_proj, Wtu, HH, II, HE);
  transpose_cvt<<<dim3((II >> 6) * (HH >> 6), NE), 256, 0, stream>>>(down_proj, Wtd, II, HH, IE);
  ext_fill_pair<<<(NE * II + 255) / 256, 256, 0, stream>>>(Wtg, Wtu, gate_B, up_B);
  ext_fill_down<<<(NE * HH + 255) / 256, 256, 0, stream>>>(Wtd, down_B);
  gather_x<<<ROWCAP, 256, 0, stream>>>(x, row_token, Xg);
  xa_kernel<<<ROWCAP, 256, 0, stream>>>(x, gate_A, up_A, row_token, row_expert, Xg);
  gemm1_kernel<<<MT_MAX * (II / 128), 256, 0, stream>>>(Xg, Wtg, Wtu, tile_e, tile_r0, hbuf);
  ha_kernel<<<ROWCAP, 256, 0, stream>>>(hbuf, down_A, row_expert, hbuf);
  gemm2_kernel<<<MT_MAX * (HH / 128), 256, 0, stream>>>(hbuf, Wtd, tile_e, tile_r0,
                                                        row_token, row_w, out);
}